// Round 4
// baseline (190.516 us; speedup 1.0000x reference)
//
#include <hip/hip_runtime.h>
#include <hip/hip_bf16.h>
#include <math.h>

// DiscriminationLoss via MFMA:
//   S[k,c] = sum_{p: label[p]=k} pred[c,p],  N[k] = |{p: label[p]=k}|, k=1..32
//   A[k]   = N[k] * sum_c S[k,c]^2
//   L      = sum_{i<j} log(max(3 - sqrt(A_i + A_j), 0)^2 + 1);  out = L*(K-1)/K
//
// R4: segmented sum as one-hot matmul on the matrix pipe.
//   D[32 seg x 32 col] += onehot(labels)[32 x 16 px] * B[16 px x 32]
//   B cols 0..7 = pred channels (bf16), col 8 = 1.0 (counts), cols 9..31 = 0.
// Rationale: R1/R2 measured LDS atomics ~3cyc/lane (>=60us floor); R3's
// predicated-register sweep is ~890 VALU / 4 pixels (>=60us VALU floor).
// MFMA does the scatter-reduce at ~0.5 cyc/pixel.

typedef __attribute__((ext_vector_type(8)))  short short8;
typedef __attribute__((ext_vector_type(16))) float f32x16;

constexpr int NSEGF = 32;            // fast-path segments 1..32 (label 0 = bg, dropped)
constexpr int RPS   = 9;             // 8 channels + count
constexpr int NROWS = NSEGF * RPS;   // 288 reduced rows
constexpr int BLK   = 256;
constexpr int NBLK  = 1024;          // 4 blocks/CU
constexpr int NWAVE = NBLK * 4;
constexpr int TILE  = 256;           // pixels per wave-tile (16 MFMA k-tiles)
constexpr int PARTBASE = 512;        // ws float offset of per-block partials

__device__ __forceinline__ unsigned cvt_pk_bf16(float lo, float hi) {
  unsigned r;
  asm("v_cvt_pk_bf16_f32 %0, %1, %2" : "=v"(r) : "v"(lo), "v"(hi));
  return r;
}

__device__ __forceinline__ float wave_sum64(float x) {
  int t;
  t = __builtin_amdgcn_update_dpp(0, __float_as_int(x), 0x111, 0xf, 0xf, true); x += __int_as_float(t);
  t = __builtin_amdgcn_update_dpp(0, __float_as_int(x), 0x112, 0xf, 0xf, true); x += __int_as_float(t);
  t = __builtin_amdgcn_update_dpp(0, __float_as_int(x), 0x114, 0xf, 0xf, true); x += __int_as_float(t);
  t = __builtin_amdgcn_update_dpp(0, __float_as_int(x), 0x118, 0xf, 0xf, true); x += __int_as_float(t);
  t = __builtin_amdgcn_update_dpp(0, __float_as_int(x), 0x142, 0xf, 0xf, true); x += __int_as_float(t);
  t = __builtin_amdgcn_update_dpp(0, __float_as_int(x), 0x143, 0xf, 0xf, true); x += __int_as_float(t);
  return x;  // lane 63 holds the sum
}

union ABf { unsigned u[4]; short8 v; };

__global__ __launch_bounds__(BLK, 4)
void seg_mfma(const float4* __restrict__ pred4,
              const int*   __restrict__ lab,
              float*       __restrict__ ws,
              int P) {
  __shared__ int   labL[4][TILE];
  __shared__ float red[4][NROWS];
  const int tid   = threadIdx.x;
  const int wid   = tid >> 6;
  const int lane  = tid & 63;
  const int col   = lane & 31;   // D col: 0..7 channel, 8 count, 9..31 unused
  const int hi    = lane >> 5;   // k-half
  const int myseg = col + 1;     // A row 'col' accumulates segment col+1

  const int P4 = P >> 2;
  const int ntiles = (P + TILE - 1) / TILE;
  const int gw = blockIdx.x * 4 + wid;

  f32x16 acc;
#pragma unroll
  for (int i = 0; i < 16; ++i) acc[i] = 0.f;

  const float4* mychan = pred4 + (size_t)col * P4;  // meaningful only for col<8
  int* labw = labL[wid];

  for (int tile = gw; tile < ntiles; tile += NWAVE) {
    const int p0 = tile * TILE;
    const bool full = (p0 + TILE <= P);

    // Stage this tile's 256 labels into the wave's LDS slice.
    if (full) {
      const int4 lv = *(const int4*)&lab[p0 + lane * 4];
      *(int4*)&labw[lane * 4] = lv;
    } else {
      int4 lv;
      const int b = p0 + lane * 4;
      lv.x = (b + 0 < P) ? lab[b + 0] : 0;
      lv.y = (b + 1 < P) ? lab[b + 1] : 0;
      lv.z = (b + 2 < P) ? lab[b + 2] : 0;
      lv.w = (b + 3 < P) ? lab[b + 3] : 0;
      *(int4*)&labw[lane * 4] = lv;
    }
    // wave-private LDS slice: compiler inserts lgkmcnt wait; no barrier needed.

    float4 bA, bB;
    auto loadB = [&](int t, float4& x, float4& y) {
      if (col < 8) {
        const int q = p0 + t * 16 + hi * 8;
        if (full) {
          x = mychan[q >> 2];
          y = mychan[(q >> 2) + 1];
        } else {
          const float* f = (const float*)mychan;
#pragma unroll
          for (int j = 0; j < 4; ++j) ((float*)&x)[j] = (q + j     < P) ? f[q + j]     : 0.f;
#pragma unroll
          for (int j = 0; j < 4; ++j) ((float*)&y)[j] = (q + 4 + j < P) ? f[q + 4 + j] : 0.f;
        }
      }
    };

    loadB(0, bA, bB);
#pragma unroll
    for (int t = 0; t < 16; ++t) {
      float4 nA, nB;
      if (t < 15) loadB(t + 1, nA, nB);

      // A fragment: one-hot of the 8 labels in this lane's k-slots.
      const int4 la = *(const int4*)&labw[t * 16 + hi * 8];
      const int4 lb = *(const int4*)&labw[t * 16 + hi * 8 + 4];
      ABf A;
      A.u[0] = ((la.x == myseg) ? 0x3F80u : 0u) | ((la.y == myseg) ? 0x3F800000u : 0u);
      A.u[1] = ((la.z == myseg) ? 0x3F80u : 0u) | ((la.w == myseg) ? 0x3F800000u : 0u);
      A.u[2] = ((lb.x == myseg) ? 0x3F80u : 0u) | ((lb.y == myseg) ? 0x3F800000u : 0u);
      A.u[3] = ((lb.z == myseg) ? 0x3F80u : 0u) | ((lb.w == myseg) ? 0x3F800000u : 0u);

      // B fragment: pred (bf16) for cols 0..7, ones for col 8, zero elsewhere.
      ABf B;
      if (col < 8) {
        B.u[0] = cvt_pk_bf16(bA.x, bA.y);
        B.u[1] = cvt_pk_bf16(bA.z, bA.w);
        B.u[2] = cvt_pk_bf16(bB.x, bB.y);
        B.u[3] = cvt_pk_bf16(bB.z, bB.w);
      } else if (col == 8) {
        if (full) {
          B.u[0] = B.u[1] = B.u[2] = B.u[3] = 0x3F803F80u;
        } else {
          const int q = p0 + t * 16 + hi * 8;
#pragma unroll
          for (int w = 0; w < 4; ++w)
            B.u[w] = ((q + 2 * w     < P) ? 0x3F80u : 0u) |
                     ((q + 2 * w + 1 < P) ? 0x3F800000u : 0u);
        }
      } else {
        B.u[0] = B.u[1] = B.u[2] = B.u[3] = 0u;
      }

      acc = __builtin_amdgcn_mfma_f32_32x32x16_bf16(A.v, B.v, acc, 0, 0, 0);
      bA = nA; bB = nB;
    }
  }

  // Extract D (verified layout: col=lane&31, row=(reg&3)+8*(reg>>2)+4*hi).
  if (col < RPS) {
#pragma unroll
    for (int r = 0; r < 16; ++r) {
      const int row = (r & 3) + 8 * (r >> 2) + 4 * hi;  // 0..31 -> segment row
      red[wid][row * RPS + col] = acc[r];
    }
  }
  __syncthreads();
  for (int v = tid; v < NROWS; v += BLK) {
    const float s = red[0][v] + red[1][v] + red[2][v] + red[3][v];
    ws[PARTBASE + (size_t)v * NBLK + blockIdx.x] = s;
  }
}

__global__ __launch_bounds__(256)
void reduce_partials(float* __restrict__ ws) {
  const int row = blockIdx.x;
  const float* r = ws + PARTBASE + (size_t)row * NBLK;
  float s = 0.f;
  for (int b = threadIdx.x; b < NBLK; b += 256) s += r[b];
  s = wave_sum64(s);
  __shared__ float ps[4];
  if ((threadIdx.x & 63) == 63) ps[threadIdx.x >> 6] = s;
  __syncthreads();
  if (threadIdx.x == 0) ws[row] = ps[0] + ps[1] + ps[2] + ps[3];
}

// Fallback (C != 8 or unaligned P or tiny ws): LDS-atomic path, same row layout.
__global__ __launch_bounds__(BLK)
void seg_gen(const float* __restrict__ pred,
             const int*   __restrict__ lab,
             float*       __restrict__ ws,
             int P, int C) {
  __shared__ float bins[(NSEGF + 1) * RPS];
  const int tid = threadIdx.x;
  for (int i = tid; i < (NSEGF + 1) * RPS; i += BLK) bins[i] = 0.f;
  __syncthreads();
  const int stride = gridDim.x * BLK;
  const int Cc = C < 8 ? C : 8;
  for (int p = blockIdx.x * BLK + tid; p < P; p += stride) {
    int lb = lab[p]; if (lb < 0) lb = 0; if (lb > NSEGF) lb = NSEGF;
    const int o = lb * RPS;
    unsafeAtomicAdd(&bins[o + 8], 1.f);
    for (int c = 0; c < Cc; ++c)
      unsafeAtomicAdd(&bins[o + c], pred[(size_t)c * P + p]);
  }
  __syncthreads();
  // segments 1..32 -> ws rows (k-1)*RPS + c
  for (int i = tid; i < NSEGF * RPS; i += BLK) {
    const float v = bins[RPS + i];
    if (v != 0.f) unsafeAtomicAdd(&ws[i], v);
  }
}

__global__ __launch_bounds__(64)
void finish_kernel(const float* __restrict__ ws,
                   const int*   __restrict__ nkp,
                   float*       __restrict__ out,
                   int C) {
  __shared__ float sA[NSEGF + 1];
  int K = *nkp; if (K > NSEGF) K = NSEGF;
  const int tid = threadIdx.x;
  const int Cc = C < 8 ? C : 8;
  for (int k = tid; k <= NSEGF; k += 64) sA[k] = 0.f;
  __syncthreads();
  for (int k = 1 + tid; k <= K; k += 64) {
    float s2 = 0.f;
    for (int c = 0; c < Cc; ++c) {
      const float v = ws[(k - 1) * RPS + c];
      s2 = fmaf(v, v, s2);
    }
    sA[k] = ws[(k - 1) * RPS + 8] * s2;
  }
  __syncthreads();

  float acc = 0.f;
  int idx = 0;
  for (int i = 1; i <= K; ++i) {
    for (int j = i + 1; j <= K; ++j) {
      if ((idx & 63) == tid) {
        const float ps = sA[i] + sA[j];
        const float d = fmaxf(3.0f - sqrtf(ps), 0.f);
        acc += logf(fmaf(d, d, 1.f));
      }
      ++idx;
    }
  }
#pragma unroll
  for (int off = 32; off > 0; off >>= 1) acc += __shfl_down(acc, off);
  if (tid == 0) out[0] = acc * (float)(K - 1) / (float)K;
}

extern "C" void kernel_launch(void* const* d_in, const int* in_sizes, int n_in,
                              void* d_out, int out_size, void* d_ws, size_t ws_size,
                              hipStream_t stream) {
  const float* pred = (const float*)d_in[0];
  const int*   lab  = (const int*)d_in[2];
  const int*   nkp  = (const int*)d_in[3];
  float*       out  = (float*)d_out;
  float*       ws   = (float*)d_ws;

  const int P = in_sizes[2];        // H*W
  const int C = in_sizes[0] / P;    // channels

  const size_t need = (size_t)(PARTBASE + NROWS * NBLK) * sizeof(float);
  const bool fast = (C == 8) && (P % 4) == 0 && ws_size >= need;

  if (fast) {
    seg_mfma<<<NBLK, BLK, 0, stream>>>((const float4*)pred, lab, ws, P);
    reduce_partials<<<NROWS, 256, 0, stream>>>(ws);
  } else {
    hipMemsetAsync(d_ws, 0, NROWS * sizeof(float), stream);
    seg_gen<<<1024, BLK, 0, stream>>>(pred, lab, ws, P, C);
  }
  finish_kernel<<<1, 64, 0, stream>>>(ws, nkp, out, C);
}

// Round 5
// 128.748 us; speedup vs baseline: 1.4798x; 1.4798x over previous
//
#include <hip/hip_runtime.h>
#include <hip/hip_bf16.h>
#include <math.h>

// DiscriminationLoss via MFMA (R5: scratch-proof rewrite of R4):
//   S[k,c] = sum_{p: label[p]=k} pred[c,p],  N[k] = |{p: label[p]=k}|, k=1..32
//   A[k]   = N[k] * sum_c S[k,c]^2
//   L      = sum_{i<j} log(max(3 - sqrt(A_i + A_j), 0)^2 + 1);  out = L*(K-1)/K
//
//   D[32 seg x 32 col] += onehot(labels)[32 x 16 px] * B[16 px x 32]
//   B cols 0..7 = pred channels (bf16), col 8 = 1.0 (counts), cols 9..31 = 0.
// R4 lesson: lambdas/unions/address-taken float4s put fragments in scratch ->
// 187 MB of HBM writes. R5 uses only named ext-vector regs with compile-time
// element indexing; labels via broadcast int4 global loads; no prefetch code.

typedef __attribute__((ext_vector_type(8)))  short short8;
typedef __attribute__((ext_vector_type(16))) float f32x16;

constexpr int NSEGF = 32;            // segments 1..32 (label 0 = background, dropped)
constexpr int RPS   = 9;             // 8 channels + count
constexpr int NROWS = NSEGF * RPS;   // 288 reduced rows
constexpr int BLK   = 256;
constexpr int NBLK  = 1024;          // 4 blocks/CU
constexpr int WPB   = BLK / 64;
constexpr int NWAVE = NBLK * WPB;
constexpr int TILE  = 256;           // pixels per wave-tile (16 MFMA k-steps)
constexpr int PARTBASE = 512;        // ws float offset of per-block partials

__device__ __forceinline__ float wave_sum64(float x) {
  int t;
  t = __builtin_amdgcn_update_dpp(0, __float_as_int(x), 0x111, 0xf, 0xf, true); x += __int_as_float(t);
  t = __builtin_amdgcn_update_dpp(0, __float_as_int(x), 0x112, 0xf, 0xf, true); x += __int_as_float(t);
  t = __builtin_amdgcn_update_dpp(0, __float_as_int(x), 0x114, 0xf, 0xf, true); x += __int_as_float(t);
  t = __builtin_amdgcn_update_dpp(0, __float_as_int(x), 0x118, 0xf, 0xf, true); x += __int_as_float(t);
  t = __builtin_amdgcn_update_dpp(0, __float_as_int(x), 0x142, 0xf, 0xf, true); x += __int_as_float(t);
  t = __builtin_amdgcn_update_dpp(0, __float_as_int(x), 0x143, 0xf, 0xf, true); x += __int_as_float(t);
  return x;  // lane 63 holds the sum
}

__device__ __forceinline__ short f2bf(float f) {
  return (short)__bfloat16_as_ushort(__float2bfloat16(f));
}

__global__ __launch_bounds__(BLK, 4)
void seg_mfma(const float4* __restrict__ pred4,
              const int4*  __restrict__ lab4,
              float*       __restrict__ ws,
              int P) {
  __shared__ float red[WPB][NROWS];
  const int tid   = threadIdx.x;
  const int wid   = tid >> 6;
  const int lane  = tid & 63;
  const int col   = lane & 31;   // D col: 0..7 channel, 8 count, 9..31 unused
  const int hi    = lane >> 5;   // k-half
  const int myseg = col + 1;     // A row 'col' accumulates segment col+1

  const int P4     = P >> 2;
  const int ntiles = P / TILE;   // fast path requires P % TILE == 0
  const int gw     = blockIdx.x * WPB + wid;

  f32x16 acc;
#pragma unroll
  for (int i = 0; i < 16; ++i) acc[i] = 0.f;

  const bool isch = (col < 8);
  const float4* mychan = pred4 + (size_t)(isch ? col : 0) * P4;

  // Constant B fragment for non-channel cols (col 8 = ones -> counts).
  short8 Bconst;
  {
    const short v = (col == 8) ? (short)0x3F80 : (short)0;
#pragma unroll
    for (int i = 0; i < 8; ++i) Bconst[i] = v;
  }

  for (int tile = gw; tile < ntiles; tile += NWAVE) {
    const int p0  = tile * TILE;
    const int lb0 = (p0 >> 2) + hi * 2;   // int4 index of this half's labels

#pragma unroll
    for (int t = 0; t < 16; ++t) {
      // 8 labels for this lane's k-slots (broadcast across the half-wave).
      const int4 la = lab4[lb0 + t * 4];
      const int4 lc = lab4[lb0 + t * 4 + 1];
      short8 A;
      const short one = (short)0x3F80;   // bf16 1.0
      A[0] = (la.x == myseg) ? one : (short)0;
      A[1] = (la.y == myseg) ? one : (short)0;
      A[2] = (la.z == myseg) ? one : (short)0;
      A[3] = (la.w == myseg) ? one : (short)0;
      A[4] = (lc.x == myseg) ? one : (short)0;
      A[5] = (lc.y == myseg) ? one : (short)0;
      A[6] = (lc.z == myseg) ? one : (short)0;
      A[7] = (lc.w == myseg) ? one : (short)0;

      short8 B = Bconst;
      if (isch) {
        const int q4 = (p0 + t * 16 + hi * 8) >> 2;
        const float4 x = mychan[q4];
        const float4 y = mychan[q4 + 1];
        B[0] = f2bf(x.x); B[1] = f2bf(x.y); B[2] = f2bf(x.z); B[3] = f2bf(x.w);
        B[4] = f2bf(y.x); B[5] = f2bf(y.y); B[6] = f2bf(y.z); B[7] = f2bf(y.w);
      }

      acc = __builtin_amdgcn_mfma_f32_32x32x16_bf16(A, B, acc, 0, 0, 0);
    }
  }

  // D layout (m74/m101-verified, confirmed by R4 pass):
  //   col = lane&31, row = (reg&3) + 8*(reg>>2) + 4*(lane>>5)
  if (col < RPS) {
#pragma unroll
    for (int r = 0; r < 16; ++r) {
      const int row = (r & 3) + 8 * (r >> 2) + 4 * hi;   // segment row-1... (row = seg-1)
      red[wid][row * RPS + col] = acc[r];
    }
  }
  __syncthreads();
  for (int v = tid; v < NROWS; v += BLK) {
    float s = 0.f;
#pragma unroll
    for (int w = 0; w < WPB; ++w) s += red[w][v];
    // Transposed partials: each block owns a contiguous 288-float slab.
    ws[PARTBASE + (size_t)blockIdx.x * NROWS + v] = s;
  }
}

__global__ __launch_bounds__(256)
void reduce_partials(float* __restrict__ ws) {
  const int row = blockIdx.x;
  float s = 0.f;
  for (int b = threadIdx.x; b < NBLK; b += 256)
    s += ws[PARTBASE + (size_t)b * NROWS + row];
  s = wave_sum64(s);
  __shared__ float ps[4];
  if ((threadIdx.x & 63) == 63) ps[threadIdx.x >> 6] = s;
  __syncthreads();
  if (threadIdx.x == 0) ws[row] = ps[0] + ps[1] + ps[2] + ps[3];
}

// Fallback (C != 8 or P % 256 != 0 or tiny ws): LDS-atomic path, same row layout.
__global__ __launch_bounds__(BLK)
void seg_gen(const float* __restrict__ pred,
             const int*   __restrict__ lab,
             float*       __restrict__ ws,
             int P, int C) {
  __shared__ float bins[(NSEGF + 1) * RPS];
  const int tid = threadIdx.x;
  for (int i = tid; i < (NSEGF + 1) * RPS; i += BLK) bins[i] = 0.f;
  __syncthreads();
  const int stride = gridDim.x * BLK;
  const int Cc = C < 8 ? C : 8;
  for (int p = blockIdx.x * BLK + tid; p < P; p += stride) {
    int lb = lab[p]; if (lb < 0) lb = 0; if (lb > NSEGF) lb = NSEGF;
    const int o = lb * RPS;
    unsafeAtomicAdd(&bins[o + 8], 1.f);
    for (int c = 0; c < Cc; ++c)
      unsafeAtomicAdd(&bins[o + c], pred[(size_t)c * P + p]);
  }
  __syncthreads();
  for (int i = tid; i < NSEGF * RPS; i += BLK) {
    const float v = bins[RPS + i];   // segments 1..32 -> rows (k-1)*RPS + c
    if (v != 0.f) unsafeAtomicAdd(&ws[i], v);
  }
}

__global__ __launch_bounds__(64)
void finish_kernel(const float* __restrict__ ws,
                   const int*   __restrict__ nkp,
                   float*       __restrict__ out,
                   int C) {
  __shared__ float sA[NSEGF + 1];
  int K = *nkp; if (K > NSEGF) K = NSEGF;
  const int tid = threadIdx.x;
  const int Cc = C < 8 ? C : 8;
  for (int k = tid; k <= NSEGF; k += 64) sA[k] = 0.f;
  __syncthreads();
  for (int k = 1 + tid; k <= K; k += 64) {
    float s2 = 0.f;
    for (int c = 0; c < Cc; ++c) {
      const float v = ws[(k - 1) * RPS + c];
      s2 = fmaf(v, v, s2);
    }
    sA[k] = ws[(k - 1) * RPS + 8] * s2;
  }
  __syncthreads();

  float acc = 0.f;
  int idx = 0;
  for (int i = 1; i <= K; ++i) {
    for (int j = i + 1; j <= K; ++j) {
      if ((idx & 63) == tid) {
        const float ps = sA[i] + sA[j];
        const float d = fmaxf(3.0f - sqrtf(ps), 0.f);
        acc += logf(fmaf(d, d, 1.f));
      }
      ++idx;
    }
  }
#pragma unroll
  for (int off = 32; off > 0; off >>= 1) acc += __shfl_down(acc, off);
  if (tid == 0) out[0] = acc * (float)(K - 1) / (float)K;
}

extern "C" void kernel_launch(void* const* d_in, const int* in_sizes, int n_in,
                              void* d_out, int out_size, void* d_ws, size_t ws_size,
                              hipStream_t stream) {
  const float* pred = (const float*)d_in[0];
  const int*   lab  = (const int*)d_in[2];
  const int*   nkp  = (const int*)d_in[3];
  float*       out  = (float*)d_out;
  float*       ws   = (float*)d_ws;

  const int P = in_sizes[2];        // H*W
  const int C = in_sizes[0] / P;    // channels

  const size_t need = (size_t)(PARTBASE + (size_t)NBLK * NROWS) * sizeof(float);
  const bool fast = (C == 8) && (P % TILE) == 0 && ws_size >= need;

  if (fast) {
    seg_mfma<<<NBLK, BLK, 0, stream>>>((const float4*)pred, (const int4*)lab, ws, P);
    reduce_partials<<<NROWS, 256, 0, stream>>>(ws);
  } else {
    hipMemsetAsync(d_ws, 0, NROWS * sizeof(float), stream);
    seg_gen<<<1024, BLK, 0, stream>>>(pred, lab, ws, P, C);
  }
  finish_kernel<<<1, 64, 0, stream>>>(ws, nkp, out, C);
}

// Round 6
// 56.241 us; speedup vs baseline: 3.3875x; 2.2892x over previous
//
#include <hip/hip_runtime.h>
#include <hip/hip_bf16.h>
#include <math.h>

// DiscriminationLoss via MFMA (R6):
//   S[k,c] = sum_{p: label[p]=k} pred[c,p],  N[k] = |{p: label[p]=k}|, k=1..32
//   A[k]   = N[k] * sum_c S[k,c]^2
//   L      = sum_{i<j} log(max(3 - sqrt(A_i + A_j), 0)^2 + 1);  out = L*(K-1)/K
//
//   D[32 seg x 32 col] += onehot(labels)[32 x 16 px] * B[16 px x 32]
//   B cols 0..7 = pred channels (bf16), col 8 = 1.0 (counts), cols 9..31 = 0.
//
// R5 lessons: (1) single-lane-at-a-time pair loop in finish = 90us serial
// transcendentals -> parallel flat pair loop. (2) VGPR=32 made the compiler
// serialize all global loads (latency-bound, 16% VALU) -> R6 stages tiles
// through registers into double-buffered LDS: loads issued at loop top,
// consumed at loop bottom, MFMA compute in between hides latency.

typedef __attribute__((ext_vector_type(8)))  short short8;
typedef __attribute__((ext_vector_type(16))) float f32x16;

constexpr int NSEGF  = 32;            // segments 1..32 (label 0 = background, dropped)
constexpr int RPS    = 9;             // 8 channels + count
constexpr int NROWS  = NSEGF * RPS;   // 288 reduced rows
constexpr int BLK    = 256;
constexpr int WPB    = 4;             // waves per block
constexpr int NBLK   = 2048;
constexpr int NWAVE  = NBLK * WPB;    // 8192 waves
constexpr int TILE   = 128;           // pixels per wave-tile = 8 MFMA k-steps
constexpr int KSTEPS = TILE / 16;     // 8
constexpr int PPAD   = 136;           // padded px per channel row (272B, 16B-aligned, bank-spread)
constexpr int PARTBASE = 512;         // ws float offset of per-block partials

__device__ __forceinline__ float wave_sum64(float x) {
  int t;
  t = __builtin_amdgcn_update_dpp(0, __float_as_int(x), 0x111, 0xf, 0xf, true); x += __int_as_float(t);
  t = __builtin_amdgcn_update_dpp(0, __float_as_int(x), 0x112, 0xf, 0xf, true); x += __int_as_float(t);
  t = __builtin_amdgcn_update_dpp(0, __float_as_int(x), 0x114, 0xf, 0xf, true); x += __int_as_float(t);
  t = __builtin_amdgcn_update_dpp(0, __float_as_int(x), 0x118, 0xf, 0xf, true); x += __int_as_float(t);
  t = __builtin_amdgcn_update_dpp(0, __float_as_int(x), 0x142, 0xf, 0xf, true); x += __int_as_float(t);
  t = __builtin_amdgcn_update_dpp(0, __float_as_int(x), 0x143, 0xf, 0xf, true); x += __int_as_float(t);
  return x;  // lane 63 holds the sum
}

__device__ __forceinline__ unsigned pkbf(float a, float b) {
  const unsigned lo = (unsigned)__bfloat16_as_ushort(__float2bfloat16(a));
  const unsigned hi = (unsigned)__bfloat16_as_ushort(__float2bfloat16(b));
  return lo | (hi << 16);
}

__global__ __launch_bounds__(BLK, 6)
void seg_mfma(const float* __restrict__ pred,
              const int*   __restrict__ lab,
              float*       __restrict__ ws,
              int P) {
  __shared__ __align__(16) unsigned short predL[WPB][2][8][PPAD];  // bf16 bits
  __shared__ __align__(16) int            labL[WPB][2][TILE];
  __shared__ float red[WPB][NROWS];

  const int tid   = threadIdx.x;
  const int wid   = tid >> 6;
  const int lane  = tid & 63;
  const int col   = lane & 31;   // D col: 0..7 channel, 8 count, 9..31 unused
  const int hi    = lane >> 5;   // k-half
  const int myseg = col + 1;     // A row 'col' accumulates segment col+1

  const int ntiles = P / TILE;   // fast path requires P % TILE == 0
  const int gw     = blockIdx.x * WPB + wid;

  // Staging assignment: lane -> (channel sc, 16-px chunk at spc).
  const int sc  = lane >> 3;
  const int spc = (lane & 7) * 16;
  const float* sbase = pred + (size_t)sc * P + spc;

  f32x16 acc;
#pragma unroll
  for (int i = 0; i < 16; ++i) acc[i] = 0.f;

  short8 Bconst;   // col 8 -> bf16 1.0 (counts); other non-channel cols -> 0
  {
    const short v = (col == 8) ? (short)0x3F80 : (short)0;
#pragma unroll
    for (int i = 0; i < 8; ++i) Bconst[i] = v;
  }

  int   cur = 0;
  int   tile = gw;
  float4 f0, f1, f2, f3;
  int2   lv;

  // Prologue: stage first tile into buffer 0.
  if (tile < ntiles) {
    const float* s = sbase + (size_t)tile * TILE;
    f0 = *(const float4*)(s);
    f1 = *(const float4*)(s + 4);
    f2 = *(const float4*)(s + 8);
    f3 = *(const float4*)(s + 12);
    lv = *(const int2*)&lab[tile * TILE + lane * 2];
    const unsigned u0 = pkbf(f0.x, f0.y), u1 = pkbf(f0.z, f0.w);
    const unsigned u2 = pkbf(f1.x, f1.y), u3 = pkbf(f1.z, f1.w);
    const unsigned u4 = pkbf(f2.x, f2.y), u5 = pkbf(f2.z, f2.w);
    const unsigned u6 = pkbf(f3.x, f3.y), u7 = pkbf(f3.z, f3.w);
    *(int4*)&predL[wid][0][sc][spc]     = make_int4((int)u0, (int)u1, (int)u2, (int)u3);
    *(int4*)&predL[wid][0][sc][spc + 8] = make_int4((int)u4, (int)u5, (int)u6, (int)u7);
    *(int2*)&labL[wid][0][lane * 2]     = lv;
  }

  while (tile < ntiles) {
    const int nt = tile + NWAVE;

    // Issue next tile's global loads EARLY (consumed after compute).
    if (nt < ntiles) {
      const float* s = sbase + (size_t)nt * TILE;
      f0 = *(const float4*)(s);
      f1 = *(const float4*)(s + 4);
      f2 = *(const float4*)(s + 8);
      f3 = *(const float4*)(s + 12);
      lv = *(const int2*)&lab[nt * TILE + lane * 2];
    }

    // Compute current tile from LDS.
#pragma unroll
    for (int t = 0; t < KSTEPS; ++t) {
      const int4 la = *(const int4*)&labL[wid][cur][t * 16 + hi * 8];
      const int4 lc = *(const int4*)&labL[wid][cur][t * 16 + hi * 8 + 4];
      short8 A;
      const short one = (short)0x3F80;
      A[0] = (la.x == myseg) ? one : (short)0;
      A[1] = (la.y == myseg) ? one : (short)0;
      A[2] = (la.z == myseg) ? one : (short)0;
      A[3] = (la.w == myseg) ? one : (short)0;
      A[4] = (lc.x == myseg) ? one : (short)0;
      A[5] = (lc.y == myseg) ? one : (short)0;
      A[6] = (lc.z == myseg) ? one : (short)0;
      A[7] = (lc.w == myseg) ? one : (short)0;

      short8 B;
      if (col < 8) {
        B = *(const short8*)&predL[wid][cur][col][t * 16 + hi * 8];
      } else {
        B = Bconst;
      }
      acc = __builtin_amdgcn_mfma_f32_32x32x16_bf16(A, B, acc, 0, 0, 0);
    }

    // Write staged regs into the other buffer (compiler inserts the vmcnt wait).
    if (nt < ntiles) {
      const int nb = cur ^ 1;
      const unsigned u0 = pkbf(f0.x, f0.y), u1 = pkbf(f0.z, f0.w);
      const unsigned u2 = pkbf(f1.x, f1.y), u3 = pkbf(f1.z, f1.w);
      const unsigned u4 = pkbf(f2.x, f2.y), u5 = pkbf(f2.z, f2.w);
      const unsigned u6 = pkbf(f3.x, f3.y), u7 = pkbf(f3.z, f3.w);
      *(int4*)&predL[wid][nb][sc][spc]     = make_int4((int)u0, (int)u1, (int)u2, (int)u3);
      *(int4*)&predL[wid][nb][sc][spc + 8] = make_int4((int)u4, (int)u5, (int)u6, (int)u7);
      *(int2*)&labL[wid][nb][lane * 2]     = lv;
    }
    cur ^= 1;
    tile = nt;
  }

  // D layout (m74/m101-verified, confirmed by R4/R5 pass):
  //   col = lane&31, row = (reg&3) + 8*(reg>>2) + 4*(lane>>5); segment = row+1
  if (col < RPS) {
#pragma unroll
    for (int r = 0; r < 16; ++r) {
      const int row = (r & 3) + 8 * (r >> 2) + 4 * hi;
      red[wid][row * RPS + col] = acc[r];
    }
  }
  __syncthreads();
  for (int v = tid; v < NROWS; v += BLK) {
    float s = 0.f;
#pragma unroll
    for (int w = 0; w < WPB; ++w) s += red[w][v];
    ws[PARTBASE + (size_t)blockIdx.x * NROWS + v] = s;   // contiguous per-block slab
  }
}

__global__ __launch_bounds__(256)
void reduce_partials(float* __restrict__ ws) {
  const int row = blockIdx.x;
  float s = 0.f;
  for (int b = threadIdx.x; b < NBLK; b += 256)
    s += ws[PARTBASE + (size_t)b * NROWS + row];
  s = wave_sum64(s);
  __shared__ float ps[4];
  if ((threadIdx.x & 63) == 63) ps[threadIdx.x >> 6] = s;
  __syncthreads();
  if (threadIdx.x == 0) ws[row] = ps[0] + ps[1] + ps[2] + ps[3];
}

// Fallback (C != 8 or P % TILE != 0 or tiny ws): LDS-atomic path, same row layout.
__global__ __launch_bounds__(BLK)
void seg_gen(const float* __restrict__ pred,
             const int*   __restrict__ lab,
             float*       __restrict__ ws,
             int P, int C) {
  __shared__ float bins[(NSEGF + 1) * RPS];
  const int tid = threadIdx.x;
  for (int i = tid; i < (NSEGF + 1) * RPS; i += BLK) bins[i] = 0.f;
  __syncthreads();
  const int stride = gridDim.x * BLK;
  const int Cc = C < 8 ? C : 8;
  for (int p = blockIdx.x * BLK + tid; p < P; p += stride) {
    int lb = lab[p]; if (lb < 0) lb = 0; if (lb > NSEGF) lb = NSEGF;
    const int o = lb * RPS;
    unsafeAtomicAdd(&bins[o + 8], 1.f);
    for (int c = 0; c < Cc; ++c)
      unsafeAtomicAdd(&bins[o + c], pred[(size_t)c * P + p]);
  }
  __syncthreads();
  for (int i = tid; i < NSEGF * RPS; i += BLK) {
    const float v = bins[RPS + i];   // segments 1..32 -> rows (k-1)*RPS + c
    if (v != 0.f) unsafeAtomicAdd(&ws[i], v);
  }
}

__global__ __launch_bounds__(64)
void finish_kernel(const float* __restrict__ ws,
                   const int*   __restrict__ nkp,
                   float*       __restrict__ out,
                   int C) {
  __shared__ float sA[NSEGF + 1];
  int K = *nkp; if (K > NSEGF) K = NSEGF;
  const int tid = threadIdx.x;
  const int Cc = C < 8 ? C : 8;
  for (int k = tid; k <= NSEGF; k += 64) sA[k] = 0.f;
  __syncthreads();
  for (int k = 1 + tid; k <= K; k += 64) {
    float s2 = 0.f;
    for (int c = 0; c < Cc; ++c) {
      const float v = ws[(k - 1) * RPS + c];
      s2 = fmaf(v, v, s2);
    }
    sA[k] = ws[(k - 1) * RPS + 8] * s2;
  }
  __syncthreads();

  // Parallel pair loop: lane handles pairs idx, idx+64, ... (R5's one-lane-at-a
  // time guard serialized 496 transcendental bodies -> 90us).
  const int npairs = K * (K - 1) / 2;
  float accv = 0.f;
  for (int idx = tid; idx < npairs; idx += 64) {
    int i = 1, rem = idx;
    while (rem >= K - i) { rem -= K - i; ++i; }
    const int j = i + 1 + rem;
    const float ps = sA[i] + sA[j];
    const float d  = fmaxf(3.0f - sqrtf(ps), 0.f);
    accv += logf(fmaf(d, d, 1.f));
  }
#pragma unroll
  for (int off = 32; off > 0; off >>= 1) accv += __shfl_down(accv, off);
  if (tid == 0) out[0] = accv * (float)(K - 1) / (float)K;
}

extern "C" void kernel_launch(void* const* d_in, const int* in_sizes, int n_in,
                              void* d_out, int out_size, void* d_ws, size_t ws_size,
                              hipStream_t stream) {
  const float* pred = (const float*)d_in[0];
  const int*   lab  = (const int*)d_in[2];
  const int*   nkp  = (const int*)d_in[3];
  float*       out  = (float*)d_out;
  float*       ws   = (float*)d_ws;

  const int P = in_sizes[2];        // H*W
  const int C = in_sizes[0] / P;    // channels

  const size_t need = (size_t)(PARTBASE + (size_t)NBLK * NROWS) * sizeof(float);
  const bool fast = (C == 8) && (P % TILE) == 0 && ws_size >= need;

  if (fast) {
    seg_mfma<<<NBLK, BLK, 0, stream>>>(pred, lab, ws, P);
    reduce_partials<<<NROWS, 256, 0, stream>>>(ws);
  } else {
    hipMemsetAsync(d_ws, 0, NROWS * sizeof(float), stream);
    seg_gen<<<1024, BLK, 0, stream>>>(pred, lab, ws, P, C);
  }
  finish_kernel<<<1, 64, 0, stream>>>(ws, nkp, out, C);
}